// Round 19
// baseline (160.710 us; speedup 1.0000x reference)
//
#include <hip/hip_runtime.h>

#define HW 4096
#define BN_RS 0.9999950000374998f   // 1/sqrt(1+1e-5)

typedef __attribute__((ext_vector_type(8))) short  short8;
typedef __attribute__((ext_vector_type(8))) unsigned short ushort8;
typedef __attribute__((ext_vector_type(4))) unsigned short ushort4v;
typedef __attribute__((ext_vector_type(4))) float  f32x4;
typedef __attribute__((ext_vector_type(2), aligned(4))) float f32x2u;  // 4B-aligned float2
typedef __attribute__((ext_vector_type(2), aligned(8))) float f32x2a;  // 8B-aligned float2

__device__ __forceinline__ float silu_f(float v) { return v / (1.0f + __expf(-v)); }
__device__ __forceinline__ int clamp64(int v) { return v < 0 ? 0 : (v > 63 ? 63 : v); }
__device__ __forceinline__ unsigned short f2bf(float f) {
    union { float f; unsigned u; } v; v.f = f;
    unsigned r = v.u + 0x7fff + ((v.u >> 16) & 1);   // RNE
    return (unsigned short)(r >> 16);
}
__device__ __forceinline__ unsigned packbf(float lo, float hi) {
    return (unsigned)f2bf(lo) | ((unsigned)f2bf(hi) << 16);
}

// -------- pre-pass: transpose+convert X[b][ci][pos] f32 -> Xt[b][pos][ci] bf16 --------
__global__ __launch_bounds__(256) void k_xt(
    const float* __restrict__ X, unsigned short* __restrict__ Xt)
{
    const int p0  = blockIdx.x * 64;
    const int ci0 = blockIdx.y * 64;
    const int b   = blockIdx.z;
    const int tid = threadIdx.x;
    __shared__ float ld[64][65];
    #pragma unroll
    for (int it = 0; it < 4; ++it) {
        int i = tid + it * 256;
        int ci = i >> 4, c4 = (i & 15) * 4;
        float4 v = *(const float4*)&X[((size_t)(b * 512 + ci0 + ci) << 12) + p0 + c4];
        ld[ci][c4] = v.x; ld[ci][c4 + 1] = v.y; ld[ci][c4 + 2] = v.z; ld[ci][c4 + 3] = v.w;
    }
    __syncthreads();
    #pragma unroll
    for (int it = 0; it < 4; ++it) {
        int i = tid + it * 256;
        int pr = i >> 4, oc4 = (i & 15) * 4;
        ushort4v u;
        u[0] = f2bf(ld[oc4 + 0][pr]);
        u[1] = f2bf(ld[oc4 + 1][pr]);
        u[2] = f2bf(ld[oc4 + 2][pr]);
        u[3] = f2bf(ld[oc4 + 3][pr]);
        *(ushort4v*)&Xt[((size_t)(b << 12) + p0 + pr) * 512 + ci0 + oc4] = u;
    }
}

// -------- pre-pass: convert w1 f32 -> bf16 (same [co][ci] layout) --------
__global__ __launch_bounds__(256) void k_w1b(
    const float* __restrict__ W, unsigned short* __restrict__ Wb)
{
    size_t i = ((size_t)blockIdx.x * 256 + threadIdx.x) * 4;
    float4 v = *(const float4*)&W[i];
    ushort4v u;
    u[0] = f2bf(v.x); u[1] = f2bf(v.y); u[2] = f2bf(v.z); u[3] = f2bf(v.w);
    *(ushort4v*)&Wb[i] = u;
}

// ------- conv1: 1x1 conv + BN + SiLU, LDS-free MFMA GEMM (k-minor operands) -------
// 64co x 64pos per block, 4 waves 2x2 of 32x32. aF/bF are direct global
// ushort8 loads (both operands k-contiguous) -> no LDS, no barriers; ILP
// hides latency. XCD-pinned 1D grid (id%8 = x-tile%8) for L2 sharing of Xt.
template<int CO, int CIN>
__global__ __launch_bounds__(256) void k_conv1_td(
    const unsigned short* __restrict__ Xt, const unsigned short* __restrict__ Wb,
    const float* __restrict__ gg, const float* __restrict__ bb,
    float* __restrict__ Y)
{
    constexpr int NC = CO / 64;
    const int id   = blockIdx.x;
    const int low3 = id & 7;
    const int rest = id >> 3;
    const int c0i  = rest % NC;
    const int tile = (rest / NC) * 8 + low3;   // b*64 + p0g
    const int b  = tile >> 6;
    const int p0 = (tile & 63) * 64;
    const int c0 = c0i * 64;

    const int tid  = threadIdx.x;
    const int wave = tid >> 6, lane = tid & 63;
    const int wm = wave >> 1, wn = wave & 1;
    const int lrow = lane & 15, lkg = lane >> 4;

    f32x4 acc[2][2];
    #pragma unroll
    for (int i = 0; i < 2; ++i)
        #pragma unroll
        for (int j = 0; j < 2; ++j) acc[i][j] = (f32x4){0.f, 0.f, 0.f, 0.f};

    const unsigned short* ap0 = Wb + (size_t)(c0 + wm * 32 + lrow) * CIN + lkg * 8;
    const unsigned short* ap1 = ap0 + 16 * CIN;
    const unsigned short* bp0 = Xt + ((size_t)(b << 12) + p0 + wn * 32 + lrow) * CIN + lkg * 8;
    const unsigned short* bp1 = bp0 + 16 * CIN;

    #pragma unroll 4
    for (int k0 = 0; k0 < CIN; k0 += 32) {
        short8 a0 = *(const short8*)(ap0 + k0);
        short8 a1 = *(const short8*)(ap1 + k0);
        short8 b0 = *(const short8*)(bp0 + k0);
        short8 b1 = *(const short8*)(bp1 + k0);
        acc[0][0] = __builtin_amdgcn_mfma_f32_16x16x32_bf16(a0, b0, acc[0][0], 0, 0, 0);
        acc[0][1] = __builtin_amdgcn_mfma_f32_16x16x32_bf16(a0, b1, acc[0][1], 0, 0, 0);
        acc[1][0] = __builtin_amdgcn_mfma_f32_16x16x32_bf16(a1, b0, acc[1][0], 0, 0, 0);
        acc[1][1] = __builtin_amdgcn_mfma_f32_16x16x32_bf16(a1, b1, acc[1][1], 0, 0, 0);
    }

    // epilogue: D row = (lane>>4)*4 + reg, col = lane&15
    #pragma unroll
    for (int mi = 0; mi < 2; ++mi) {
        #pragma unroll
        for (int r = 0; r < 4; ++r) {
            int co = c0 + wm * 32 + mi * 16 + lkg * 4 + r;
            float s  = gg[co] * BN_RS;
            float bi = bb[co];
            size_t rowb = ((size_t)b * CO + co) * HW + p0 + wn * 32 + lrow;
            Y[rowb]      = silu_f(fmaf(acc[mi][0][r], s, bi));
            Y[rowb + 16] = silu_f(fmaf(acc[mi][1][r], s, bi));
        }
    }
}

// ---------------- conv2: 1x1 conv + BN + SiLU, bf16 MFMA GEMM (R16) ----------------
template<int CO, int CIN>
__global__ __launch_bounds__(256) void k_conv1x1_mfma(
    const float* __restrict__ X, const float* __restrict__ Wt,
    const float* __restrict__ gg, const float* __restrict__ bb,
    float* __restrict__ Y)
{
    constexpr int NC = CO / 64;
    const int id   = blockIdx.x;
    const int low3 = id & 7;
    const int rest = id >> 3;
    const int c0i  = rest % NC;
    const int tile = (rest / NC) * 8 + low3;
    const int b  = tile >> 6;
    const int p0 = (tile & 63) * 64;
    const int c0 = c0i * 64;

    const int tid  = threadIdx.x;
    const int wave = tid >> 6, lane = tid & 63;
    const int wm = wave >> 1, wn = wave & 1;
    const int lrow = lane & 15, lkg = lane >> 4;

    __shared__ __align__(16) unsigned short As[64 * 40];
    __shared__ __align__(16) unsigned short Bs[64 * 40];

    const float* Xb = X + (size_t)b * CIN * HW;

    f32x4 acc[2][2];
    #pragma unroll
    for (int i = 0; i < 2; ++i)
        #pragma unroll
        for (int j = 0; j < 2; ++j) acc[i][j] = (f32x4){0.f, 0.f, 0.f, 0.f};

    const int arow = tid >> 2, akc = (tid & 3) * 8;
    const int kp = tid >> 4, p4 = (tid & 15) * 4;

    ushort8 aP;
    uint4   bP;

    auto LOAD = [&](int k0) {
        const float* wp = &Wt[(size_t)(c0 + arow) * CIN + k0 + akc];
        float4 v0 = *(const float4*)wp;
        float4 v1 = *(const float4*)(wp + 4);
        ushort8 u;
        u[0] = f2bf(v0.x); u[1] = f2bf(v0.y); u[2] = f2bf(v0.z); u[3] = f2bf(v0.w);
        u[4] = f2bf(v1.x); u[5] = f2bf(v1.y); u[6] = f2bf(v1.z); u[7] = f2bf(v1.w);
        aP = u;
        const float* xp = &Xb[(size_t)(k0 + 2 * kp) * HW + p0 + p4];
        float4 x0 = *(const float4*)xp;
        float4 x1 = *(const float4*)(xp + HW);
        bP.x = packbf(x0.x, x1.x);
        bP.y = packbf(x0.y, x1.y);
        bP.z = packbf(x0.z, x1.z);
        bP.w = packbf(x0.w, x1.w);
    };

    LOAD(0);
    for (int k0 = 0; k0 < CIN; k0 += 32) {
        __syncthreads();
        *(ushort8*)&As[arow * 40 + akc] = aP;
        {
            const int kg = kp >> 2, kl2 = (kp & 3) * 2;
            const unsigned bw[4] = {bP.x, bP.y, bP.z, bP.w};
            #pragma unroll
            for (int jj = 0; jj < 4; ++jj) {
                int pos = p4 + jj;
                int kgs = kg ^ ((pos >> 3) & 3);
                *(unsigned*)&Bs[pos * 40 + kgs * 8 + kl2] = bw[jj];
            }
        }
        __syncthreads();
        if (k0 + 32 < CIN) LOAD(k0 + 32);

        short8 aF[2], bF[2];
        #pragma unroll
        for (int mi = 0; mi < 2; ++mi)
            aF[mi] = *(const short8*)&As[(wm * 32 + mi * 16 + lrow) * 40 + lkg * 8];
        #pragma unroll
        for (int ni = 0; ni < 2; ++ni) {
            int pos = wn * 32 + ni * 16 + lrow;
            int kgs = lkg ^ ((pos >> 3) & 3);
            bF[ni] = *(const short8*)&Bs[pos * 40 + kgs * 8];
        }
        #pragma unroll
        for (int mi = 0; mi < 2; ++mi)
            #pragma unroll
            for (int ni = 0; ni < 2; ++ni)
                acc[mi][ni] = __builtin_amdgcn_mfma_f32_16x16x32_bf16(
                    aF[mi], bF[ni], acc[mi][ni], 0, 0, 0);
    }

    #pragma unroll
    for (int mi = 0; mi < 2; ++mi) {
        #pragma unroll
        for (int r = 0; r < 4; ++r) {
            int co = c0 + wm * 32 + mi * 16 + lkg * 4 + r;
            float s  = gg[co] * BN_RS;
            float bi = bb[co];
            size_t rowb = ((size_t)b * CO + co) * HW + p0 + wn * 32 + lrow;
            Y[rowb]      = silu_f(fmaf(acc[mi][0][r], s, bi));
            Y[rowb + 16] = silu_f(fmaf(acc[mi][1][r], s, bi));
        }
    }
}

// -------- one-time: transpose offset-conv weights to [tap][co(pad32)][ci] bf16 --------
__global__ __launch_bounds__(256) void k_woff_t(
    const float* __restrict__ Wo, unsigned short* __restrict__ Wt2)
{
    const int t = blockIdx.x;      // 0..8
    const int co = blockIdx.y;     // 0..31
    const int ci = threadIdx.x;    // 0..255
    float v = (co < 18) ? Wo[((size_t)co * 256 + ci) * 9 + t] : 0.0f;
    Wt2[((size_t)t * 32 + co) * 256 + ci] = f2bf(v);
}

// -------- 3x3 conv (256 -> 18) as implicit-GEMM MFMA, ci-split partials --------
__global__ __launch_bounds__(256) void k_conv_off(
    const float* __restrict__ Hh, const unsigned short* __restrict__ Wt2,
    float* __restrict__ OffP)
{
    const int y = blockIdx.x;
    const int b = blockIdx.y;
    const int q = blockIdx.z;
    const int tid = threadIdx.x;
    const int wn = tid >> 6;
    const int lane = tid & 63;
    const int lrow = lane & 15, lkg = lane >> 4;

    __shared__ __align__(16) unsigned short hsT[3][66][40];

    f32x4 acc[2];
    acc[0] = (f32x4){0.f, 0.f, 0.f, 0.f};
    acc[1] = (f32x4){0.f, 0.f, 0.f, 0.f};

    for (int cc = 0; cc < 2; ++cc) {
        const int ci0 = q * 64 + cc * 32;
        __syncthreads();
        if (tid < 192) {
            int r = tid / 64, which = (tid >> 5) & 1, ci = tid & 31;
            hsT[r][which ? 65 : 0][ci] = 0;
        }
        #pragma unroll
        for (int it = 0; it < 6; ++it) {
            int i  = tid + it * 256;
            int r  = i >> 9;
            int ci = (i >> 4) & 31;
            int x4 = (i & 15) << 2;
            int yy = y + r - 1;
            float4 v = make_float4(0.f, 0.f, 0.f, 0.f);
            if ((unsigned)yy < 64u)
                v = *(const float4*)&Hh[((size_t)(b * 256 + ci0 + ci) << 12) + yy * 64 + x4];
            hsT[r][1 + x4 + 0][ci] = f2bf(v.x);
            hsT[r][1 + x4 + 1][ci] = f2bf(v.y);
            hsT[r][1 + x4 + 2][ci] = f2bf(v.z);
            hsT[r][1 + x4 + 3][ci] = f2bf(v.w);
        }
        __syncthreads();

        #pragma unroll
        for (int t9 = 0; t9 < 9; ++t9) {
            const int ty = t9 / 3, tx = t9 % 3;
            short8 bF = *(const short8*)&hsT[ty][wn * 16 + lrow + tx][lkg * 8];
            #pragma unroll
            for (int mi = 0; mi < 2; ++mi) {
                short8 aF = *(const short8*)&Wt2[((size_t)t9 * 32 + mi * 16 + lrow) * 256
                                                 + ci0 + lkg * 8];
                acc[mi] = __builtin_amdgcn_mfma_f32_16x16x32_bf16(aF, bF, acc[mi], 0, 0, 0);
            }
        }
    }

    #pragma unroll
    for (int mi = 0; mi < 2; ++mi) {
        #pragma unroll
        for (int r = 0; r < 4; ++r) {
            int co = mi * 16 + lkg * 4 + r;
            if (co < 18)
                OffP[(((size_t)q * 4 + b) * 18 + co) * HW + y * 64 + wn * 16 + lrow]
                    = acc[mi][r];
        }
    }
}

// -- combine 4 ci-split partials + bias -> interleaved Off2[b][9][pos][2] --
__global__ __launch_bounds__(256) void k_off_combine(
    const float* __restrict__ OffP, const float* __restrict__ Bo,
    float* __restrict__ Off2)
{
    const int bk = blockIdx.x;
    const int b = bk / 9, k = bk - b * 9;
    const int t0 = 2 * k, t1 = 2 * k + 1;
    const float bias0 = Bo[t0], bias1 = Bo[t1];
    const size_t p0 = ((size_t)b * 18 + t0) * HW;
    const size_t p1 = ((size_t)b * 18 + t1) * HW;
    float* outp = Off2 + (((size_t)b * 9 + k) * HW) * 2;
    #pragma unroll
    for (int it = 0; it < 4; ++it) {
        int p4 = (threadIdx.x + it * 256) * 4;
        float4 s0 = *(const float4*)&OffP[p0 + p4];
        float4 s1 = *(const float4*)&OffP[p1 + p4];
        #pragma unroll
        for (int q = 1; q < 4; ++q) {
            float4 v0 = *(const float4*)&OffP[((size_t)q * 4 * 18) * HW + p0 + p4];
            float4 v1 = *(const float4*)&OffP[((size_t)q * 4 * 18) * HW + p1 + p4];
            s0.x += v0.x; s0.y += v0.y; s0.z += v0.z; s0.w += v0.w;
            s1.x += v1.x; s1.y += v1.y; s1.z += v1.z; s1.w += v1.w;
        }
        s0.x += bias0; s0.y += bias0; s0.z += bias0; s0.w += bias0;
        s1.x += bias1; s1.y += bias1; s1.z += bias1; s1.w += bias1;
        float4 o01 = make_float4(s0.x, s1.x, s0.y, s1.y);
        float4 o23 = make_float4(s0.z, s1.z, s0.w, s1.w);
        *(float4*)&outp[p4 * 2]     = o01;
        *(float4*)&outp[p4 * 2 + 4] = o23;
    }
}

// ------------- deformable depthwise 3x3 + BN + SiLU + residual -------------
__global__ __launch_bounds__(256) void k_deform(
    const float* __restrict__ Hh, const float* __restrict__ Off2,
    const float* __restrict__ Wd, const float* __restrict__ Gb,
    const float* __restrict__ Bb, float* __restrict__ H2)
{
    const int idx = blockIdx.x;
    const int bq  = idx & 31;
    const int y   = idx >> 5;
    const int b   = bq >> 3;
    const int q   = bq & 7;
    const int tid = threadIdx.x;
    const int x = tid & 63;
    const int g = tid >> 6;
    const int pos = y * 64 + x;

    __shared__ __align__(16) float hsw[5][32][68];
    __shared__ __align__(16) float wds[9 * 32];
    __shared__ float gbs[32], bbs[32];

    for (int i = tid; i < 288; i += 256) {
        int lc = i & 31, k = i >> 5;
        wds[i] = Wd[(q * 32 + lc) * 9 + k];
    }
    if (tid < 32) {
        gbs[tid] = Gb[q * 32 + tid] * BN_RS;
        bbs[tid] = Bb[q * 32 + tid];
    }

    int w0 = y - 2; w0 = w0 < 0 ? 0 : (w0 > 59 ? 59 : w0);
    const float* hq = Hh + ((size_t)(b * 256 + q * 32) << 12);
    #pragma unroll
    for (int it = 0; it < 10; ++it) {
        int i = tid + it * 256;
        int slot = i >> 9, ch = (i >> 4) & 31, x4 = (i & 15) << 2;
        float4 v = *(const float4*)&hq[((size_t)ch << 12) + (w0 + slot) * 64 + x4];
        *(float4*)&hsw[slot][ch][x4] = v;
    }
    __syncthreads();

    float acc[8];
    #pragma unroll
    for (int j = 0; j < 8; ++j) acc[j] = 0.f;

    const float* Ob   = Off2 + ((size_t)b * 9 * HW + pos) * 2;
    const float* hb0  = hq + ((size_t)(g * 8) << 12);
    const float* ldsb = &hsw[0][0][0];

    for (int r = 0; r < 3; ++r) {
        int   rb0[3], rb1[3], lb0[3], lb1[3];
        float wa0[3], wb0[3], wa1[3], wb1[3];
        bool inw = true;
        #pragma unroll
        for (int t = 0; t < 3; ++t) {
            int k = r * 3 + t;
            f32x2a dv = *(const f32x2a*)(Ob + (size_t)k * HW * 2);
            float dy = dv.x, dx = dv.y;
            float py = (float)(y + r - 1) + dy;
            float px = (float)(x + t - 1) + dx;
            float fy0 = floorf(py), fx0 = floorf(px);
            int y0 = (int)fy0, x0 = (int)fx0;
            float fy = py - fy0, fx = px - fx0;
            bool vy0 = ((unsigned)y0 < 64u), vy1 = ((unsigned)(y0 + 1) < 64u);
            bool vx0 = ((unsigned)x0 < 64u), vx1 = ((unsigned)(x0 + 1) < 64u);
            int cy0 = clamp64(y0), cy1 = clamp64(y0 + 1);
            int bx  = x0 < 0 ? 0 : (x0 > 62 ? 62 : x0);
            int d0 = x0 - bx;
            bool o0 = d0 > 0;
            bool o1 = d0 >= 0;
            rb0[t] = cy0 * 64 + bx;
            rb1[t] = cy1 * 64 + bx;
            lb0[t] = (cy0 - w0) * 2176 + bx;
            lb1[t] = (cy1 - w0) * 2176 + bx;
            inw = inw && (cy0 >= w0) && (cy1 <= w0 + 4);
            float wy0 = vy0 ? (1.0f - fy) : 0.0f;
            float wy1 = vy1 ? fy : 0.0f;
            float wx0 = vx0 ? (1.0f - fx) : 0.0f;
            float wx1 = vx1 ? fx : 0.0f;
            float wa = (o0 ? 0.0f : wx0) + (o1 ? 0.0f : wx1);
            float wb = (o0 ? wx0 : 0.0f) + (o1 ? wx1 : 0.0f);
            wa0[t] = wa * wy0; wb0[t] = wb * wy0;
            wa1[t] = wa * wy1; wb1[t] = wb * wy1;
        }
        if (__all(inw)) {
            #pragma unroll
            for (int j = 0; j < 8; ++j) {
                const int chb = (g * 8 + j) * 68;
                float a = acc[j];
                #pragma unroll
                for (int t = 0; t < 3; ++t) {
                    f32x2u u0 = *(const f32x2u*)(ldsb + lb0[t] + chb);
                    f32x2u u1 = *(const f32x2u*)(ldsb + lb1[t] + chb);
                    float val = u0.x * wa0[t] + u0.y * wb0[t]
                              + u1.x * wa1[t] + u1.y * wb1[t];
                    a = fmaf(val, wds[(r * 3 + t) * 32 + g * 8 + j], a);
                }
                acc[j] = a;
            }
        } else {
            #pragma unroll
            for (int j = 0; j < 8; ++j) {
                const float* hb = hb0 + ((size_t)j << 12);
                float a = acc[j];
                #pragma unroll
                for (int t = 0; t < 3; ++t) {
                    f32x2u u0 = *(const f32x2u*)(hb + rb0[t]);
                    f32x2u u1 = *(const f32x2u*)(hb + rb1[t]);
                    float val = u0.x * wa0[t] + u0.y * wb0[t]
                              + u1.x * wa1[t] + u1.y * wb1[t];
                    a = fmaf(val, wds[(r * 3 + t) * 32 + g * 8 + j], a);
                }
                acc[j] = a;
            }
        }
    }

    const int ry = (y - w0) * 2176 + x;
    #pragma unroll
    for (int j = 0; j < 8; ++j) {
        int lc = g * 8 + j;
        float t = fmaf(acc[j], gbs[lc], bbs[lc]);
        float res = ldsb[ry + lc * 68];
        __builtin_nontemporal_store(silu_f(t) + res,
            &H2[((size_t)(b * 256 + q * 32 + lc) << 12) + pos]);
    }
}

// ---------------- SE: global mean over HxW ----------------
__global__ __launch_bounds__(256) void k_se_reduce(
    const float* __restrict__ Y, float* __restrict__ sb)
{
    const int bc = blockIdx.x;
    const float4* p = (const float4*)(Y + (size_t)bc * HW);
    int tid = threadIdx.x;
    float s = 0.f;
    #pragma unroll
    for (int it = 0; it < 4; ++it) {
        float4 v = p[tid + it * 256];
        s += v.x + v.y + v.z + v.w;
    }
    #pragma unroll
    for (int o = 32; o > 0; o >>= 1) s += __shfl_down(s, o);
    __shared__ float red[4];
    if ((tid & 63) == 0) red[tid >> 6] = s;
    __syncthreads();
    if (tid == 0) sb[bc] = (red[0] + red[1] + red[2] + red[3]) * (1.0f / 4096.0f);
}

// ---------------- SE: fc1(silu) + fc2(sigmoid) ----------------
__global__ __launch_bounds__(256) void k_se_fc(
    const float* __restrict__ sb, const float* __restrict__ wf1,
    const float* __restrict__ bf1, const float* __restrict__ wf2,
    const float* __restrict__ bf2, float* __restrict__ s2)
{
    const int b = blockIdx.x;
    const int t = threadIdx.x;
    __shared__ float sv[512];
    __shared__ float s1[32];
    sv[t]       = sb[b * 512 + t];
    sv[t + 256] = sb[b * 512 + t + 256];
    __syncthreads();
    if (t < 32) {
        float a = bf1[t];
        const float* w = wf1 + t * 512;
        for (int i = 0; i < 512; ++i) a = fmaf(w[i], sv[i], a);
        s1[t] = silu_f(a);
    }
    __syncthreads();
    #pragma unroll
    for (int it = 0; it < 2; ++it) {
        int co = t + it * 256;
        float a = bf2[co];
        const float* w = wf2 + co * 32;
        #pragma unroll
        for (int i = 0; i < 32; ++i) a = fmaf(w[i], s1[i], a);
        s2[b * 512 + co] = 1.0f / (1.0f + __expf(-a));
    }
}

// ---------------- final: out *= s ----------------
__global__ __launch_bounds__(256) void k_se_scale(
    float* __restrict__ Y, const float* __restrict__ s2)
{
    size_t i = (size_t)blockIdx.x * 256 + threadIdx.x;
    int bc = (int)(i >> 10);
    float sc = s2[bc];
    float4 v = ((float4*)Y)[i];
    v.x *= sc; v.y *= sc; v.z *= sc; v.w *= sc;
    ((float4*)Y)[i] = v;
}

extern "C" void kernel_launch(void* const* d_in, const int* in_sizes, int n_in,
                              void* d_out, int out_size, void* d_ws, size_t ws_size,
                              hipStream_t stream)
{
    const float* x   = (const float*)d_in[0];
    const float* w1  = (const float*)d_in[1];
    const float* g1  = (const float*)d_in[2];
    const float* b1  = (const float*)d_in[3];
    const float* wof = (const float*)d_in[4];
    const float* bof = (const float*)d_in[5];
    const float* wdw = (const float*)d_in[6];
    const float* gb  = (const float*)d_in[7];
    const float* bbv = (const float*)d_in[8];
    const float* w2  = (const float*)d_in[9];
    const float* g2  = (const float*)d_in[10];
    const float* b2  = (const float*)d_in[11];
    const float* wf1 = (const float*)d_in[12];
    const float* bf1 = (const float*)d_in[13];
    const float* wf2 = (const float*)d_in[14];
    const float* bf2 = (const float*)d_in[15];
    float* out = (float*)d_out;

    const size_t n_h    = 4ull * 256 * HW;        // floats
    const size_t n_offp = 4ull * 4 * 18 * HW;
    const size_t n_off  = 4ull * 18 * HW;
    const size_t n_wt2  = 9 * 32 * 256 / 2;       // float-equivalents
    const size_t n_xt   = 4ull * HW * 512 / 2;    // bf16 Xt as float-equivalents
    const size_t n_w1b  = 256 * 512 / 2;
    float* ws = (float*)d_ws;
    float *h, *offp, *offc, *h2, *sb, *s2, *wt2f, *xtf, *w1bf;
    size_t need = (2 * n_h + n_offp + n_off + 2048 + 2048 + n_wt2 + n_xt + n_w1b + 1024)
                  * sizeof(float);
    if (ws_size >= need) {
        h = ws; offp = h + n_h; offc = offp + n_offp; h2 = offc + n_off;
        sb = h2 + n_h; s2 = sb + 2048; wt2f = s2 + 2048;
        xtf = wt2f + n_wt2; w1bf = xtf + n_xt;
    } else {
        h = out;  // dead before conv2 writes out
        offp = ws; offc = offp + n_offp; h2 = offc + n_off;
        sb = h2 + n_h; s2 = sb + 2048; wt2f = s2 + 2048;
        xtf = wt2f + n_wt2; w1bf = xtf + n_xt;
    }
    unsigned short* wt2 = (unsigned short*)wt2f;
    unsigned short* xt  = (unsigned short*)xtf;
    unsigned short* w1b = (unsigned short*)w1bf;

    k_xt<<<dim3(64, 8, 4), 256, 0, stream>>>(x, xt);
    k_w1b<<<128, 256, 0, stream>>>(w1, w1b);
    k_conv1_td<256, 512><<<1024, 256, 0, stream>>>(xt, w1b, g1, b1, h);
    k_woff_t<<<dim3(9, 32), 256, 0, stream>>>(wof, wt2);
    k_conv_off<<<dim3(64, 4, 4), 256, 0, stream>>>(h, wt2, offp);
    k_off_combine<<<36, 256, 0, stream>>>(offp, bof, offc);
    k_deform<<<2048, 256, 0, stream>>>(h, offc, wdw, gb, bbv, h2);
    k_conv1x1_mfma<512, 256><<<2048, 256, 0, stream>>>(h2, w2, g2, b2, out);
    k_se_reduce<<<2048, 256, 0, stream>>>(out, sb);
    k_se_fc<<<4, 256, 0, stream>>>(sb, wf1, bf1, wf2, bf2, s2);
    k_se_scale<<<8192, 256, 0, stream>>>(out, s2);
}

// Round 20
// 133.554 us; speedup vs baseline: 1.2033x; 1.2033x over previous
//
#include <hip/hip_runtime.h>

#define HW 4096
#define BN_RS 0.9999950000374998f   // 1/sqrt(1+1e-5)

typedef __attribute__((ext_vector_type(8))) short  short8;
typedef __attribute__((ext_vector_type(8))) unsigned short ushort8;
typedef __attribute__((ext_vector_type(4))) float  f32x4;
typedef __attribute__((ext_vector_type(2), aligned(4))) float f32x2u;  // 4B-aligned float2
typedef __attribute__((ext_vector_type(2), aligned(8))) float f32x2a;  // 8B-aligned float2

__device__ __forceinline__ float silu_f(float v) { return v / (1.0f + __expf(-v)); }
__device__ __forceinline__ int clamp64(int v) { return v < 0 ? 0 : (v > 63 ? 63 : v); }
__device__ __forceinline__ unsigned short f2bf(float f) {
    union { float f; unsigned u; } v; v.f = f;
    unsigned r = v.u + 0x7fff + ((v.u >> 16) & 1);   // RNE
    return (unsigned short)(r >> 16);
}
__device__ __forceinline__ unsigned packbf(float lo, float hi) {
    return (unsigned)f2bf(lo) | ((unsigned)f2bf(hi) << 16);
}

// ---------------- 1x1 conv + BN + SiLU, bf16 MFMA GEMM ----------------
// 64co x 64pos tile, 4 waves 2x2 of 32x32, BK=32. XCD-pinned 1D grid;
// T14 async-stage (next K-tile in regs under MFMA); u32 bf16-pair B staging.
template<int CO, int CIN>
__global__ __launch_bounds__(256) void k_conv1x1_mfma(
    const float* __restrict__ X, const float* __restrict__ Wt,
    const float* __restrict__ gg, const float* __restrict__ bb,
    float* __restrict__ Y)
{
    constexpr int NC = CO / 64;
    const int id   = blockIdx.x;
    const int low3 = id & 7;
    const int rest = id >> 3;
    const int c0i  = rest % NC;
    const int tile = (rest / NC) * 8 + low3;   // b*64 + p0g, 0..255
    const int b  = tile >> 6;
    const int p0 = (tile & 63) * 64;
    const int c0 = c0i * 64;

    const int tid  = threadIdx.x;
    const int wave = tid >> 6, lane = tid & 63;
    const int wm = wave >> 1, wn = wave & 1;
    const int lrow = lane & 15, lkg = lane >> 4;

    __shared__ __align__(16) unsigned short As[64 * 40];  // [co][k]
    __shared__ __align__(16) unsigned short Bs[64 * 40];  // [pos][k], swizzle (pos>>3)&3

    const float* Xb = X + (size_t)b * CIN * HW;

    f32x4 acc[2][2];
    #pragma unroll
    for (int i = 0; i < 2; ++i)
        #pragma unroll
        for (int j = 0; j < 2; ++j) acc[i][j] = (f32x4){0.f, 0.f, 0.f, 0.f};

    const int arow = tid >> 2, akc = (tid & 3) * 8;   // A: 64 rows x 32 k
    const int kp = tid >> 4, p4 = (tid & 15) * 4;     // B: 16 k-pairs x 16 p4

    ushort8 aP;
    uint4   bP;

    auto LOAD = [&](int k0) {
        const float* wp = &Wt[(size_t)(c0 + arow) * CIN + k0 + akc];
        float4 v0 = *(const float4*)wp;
        float4 v1 = *(const float4*)(wp + 4);
        ushort8 u;
        u[0] = f2bf(v0.x); u[1] = f2bf(v0.y); u[2] = f2bf(v0.z); u[3] = f2bf(v0.w);
        u[4] = f2bf(v1.x); u[5] = f2bf(v1.y); u[6] = f2bf(v1.z); u[7] = f2bf(v1.w);
        aP = u;
        const float* xp = &Xb[(size_t)(k0 + 2 * kp) * HW + p0 + p4];
        float4 x0 = *(const float4*)xp;
        float4 x1 = *(const float4*)(xp + HW);
        bP.x = packbf(x0.x, x1.x);
        bP.y = packbf(x0.y, x1.y);
        bP.z = packbf(x0.z, x1.z);
        bP.w = packbf(x0.w, x1.w);
    };

    LOAD(0);
    for (int k0 = 0; k0 < CIN; k0 += 32) {
        __syncthreads();
        *(ushort8*)&As[arow * 40 + akc] = aP;
        {
            const int kg = kp >> 2, kl2 = (kp & 3) * 2;
            const unsigned bw[4] = {bP.x, bP.y, bP.z, bP.w};
            #pragma unroll
            for (int jj = 0; jj < 4; ++jj) {
                int pos = p4 + jj;
                int kgs = kg ^ ((pos >> 3) & 3);
                *(unsigned*)&Bs[pos * 40 + kgs * 8 + kl2] = bw[jj];
            }
        }
        __syncthreads();
        if (k0 + 32 < CIN) LOAD(k0 + 32);   // hides under MFMA below

        short8 aF[2], bF[2];
        #pragma unroll
        for (int mi = 0; mi < 2; ++mi)
            aF[mi] = *(const short8*)&As[(wm * 32 + mi * 16 + lrow) * 40 + lkg * 8];
        #pragma unroll
        for (int ni = 0; ni < 2; ++ni) {
            int pos = wn * 32 + ni * 16 + lrow;
            int kgs = lkg ^ ((pos >> 3) & 3);
            bF[ni] = *(const short8*)&Bs[pos * 40 + kgs * 8];
        }
        #pragma unroll
        for (int mi = 0; mi < 2; ++mi)
            #pragma unroll
            for (int ni = 0; ni < 2; ++ni)
                acc[mi][ni] = __builtin_amdgcn_mfma_f32_16x16x32_bf16(
                    aF[mi], bF[ni], acc[mi][ni], 0, 0, 0);
    }

    // epilogue: D row = (lane>>4)*4 + reg, col = lane&15
    #pragma unroll
    for (int mi = 0; mi < 2; ++mi) {
        #pragma unroll
        for (int r = 0; r < 4; ++r) {
            int co = c0 + wm * 32 + mi * 16 + lkg * 4 + r;
            float s  = gg[co] * BN_RS;
            float bi = bb[co];
            size_t rowb = ((size_t)b * CO + co) * HW + p0 + wn * 32 + lrow;
            Y[rowb]      = silu_f(fmaf(acc[mi][0][r], s, bi));
            Y[rowb + 16] = silu_f(fmaf(acc[mi][1][r], s, bi));
        }
    }
}

// -------- one-time: transpose offset-conv weights to [tap][co(pad32)][ci] bf16 --------
__global__ __launch_bounds__(256) void k_woff_t(
    const float* __restrict__ Wo, unsigned short* __restrict__ Wt2)
{
    const int t = blockIdx.x;      // 0..8
    const int co = blockIdx.y;     // 0..31
    const int ci = threadIdx.x;    // 0..255
    float v = (co < 18) ? Wo[((size_t)co * 256 + ci) * 9 + t] : 0.0f;
    Wt2[((size_t)t * 32 + co) * 256 + ci] = f2bf(v);
}

// -------- 3x3 conv (256 -> 18) as implicit-GEMM MFMA, ci-split partials --------
__global__ __launch_bounds__(256) void k_conv_off(
    const float* __restrict__ Hh, const unsigned short* __restrict__ Wt2,
    float* __restrict__ OffP)
{
    const int y = blockIdx.x;
    const int b = blockIdx.y;
    const int q = blockIdx.z;
    const int tid = threadIdx.x;
    const int wn = tid >> 6;
    const int lane = tid & 63;
    const int lrow = lane & 15, lkg = lane >> 4;

    __shared__ __align__(16) unsigned short hsT[3][66][40];  // [r][xx][ci], pad 40

    f32x4 acc[2];
    acc[0] = (f32x4){0.f, 0.f, 0.f, 0.f};
    acc[1] = (f32x4){0.f, 0.f, 0.f, 0.f};

    for (int cc = 0; cc < 2; ++cc) {
        const int ci0 = q * 64 + cc * 32;
        __syncthreads();
        if (tid < 192) {
            int r = tid / 64, which = (tid >> 5) & 1, ci = tid & 31;
            hsT[r][which ? 65 : 0][ci] = 0;
        }
        #pragma unroll
        for (int it = 0; it < 6; ++it) {
            int i  = tid + it * 256;       // 0..1535
            int r  = i >> 9;
            int ci = (i >> 4) & 31;
            int x4 = (i & 15) << 2;
            int yy = y + r - 1;
            float4 v = make_float4(0.f, 0.f, 0.f, 0.f);
            if ((unsigned)yy < 64u)
                v = *(const float4*)&Hh[((size_t)(b * 256 + ci0 + ci) << 12) + yy * 64 + x4];
            hsT[r][1 + x4 + 0][ci] = f2bf(v.x);
            hsT[r][1 + x4 + 1][ci] = f2bf(v.y);
            hsT[r][1 + x4 + 2][ci] = f2bf(v.z);
            hsT[r][1 + x4 + 3][ci] = f2bf(v.w);
        }
        __syncthreads();

        #pragma unroll
        for (int t9 = 0; t9 < 9; ++t9) {
            const int ty = t9 / 3, tx = t9 % 3;
            short8 bF = *(const short8*)&hsT[ty][wn * 16 + lrow + tx][lkg * 8];
            #pragma unroll
            for (int mi = 0; mi < 2; ++mi) {
                short8 aF = *(const short8*)&Wt2[((size_t)t9 * 32 + mi * 16 + lrow) * 256
                                                 + ci0 + lkg * 8];
                acc[mi] = __builtin_amdgcn_mfma_f32_16x16x32_bf16(aF, bF, acc[mi], 0, 0, 0);
            }
        }
    }

    #pragma unroll
    for (int mi = 0; mi < 2; ++mi) {
        #pragma unroll
        for (int r = 0; r < 4; ++r) {
            int co = mi * 16 + lkg * 4 + r;
            if (co < 18)
                OffP[(((size_t)q * 4 + b) * 18 + co) * HW + y * 64 + wn * 16 + lrow]
                    = acc[mi][r];
        }
    }
}

// -- combine 4 ci-split partials + bias -> interleaved Off2[b][9][pos][2] --
__global__ __launch_bounds__(256) void k_off_combine(
    const float* __restrict__ OffP, const float* __restrict__ Bo,
    float* __restrict__ Off2)
{
    const int bk = blockIdx.x;         // b*9 + k, 36 blocks
    const int b = bk / 9, k = bk - b * 9;
    const int t0 = 2 * k, t1 = 2 * k + 1;
    const float bias0 = Bo[t0], bias1 = Bo[t1];
    const size_t p0 = ((size_t)b * 18 + t0) * HW;
    const size_t p1 = ((size_t)b * 18 + t1) * HW;
    float* outp = Off2 + (((size_t)b * 9 + k) * HW) * 2;
    #pragma unroll
    for (int it = 0; it < 4; ++it) {
        int p4 = (threadIdx.x + it * 256) * 4;
        float4 s0 = *(const float4*)&OffP[p0 + p4];
        float4 s1 = *(const float4*)&OffP[p1 + p4];
        #pragma unroll
        for (int q = 1; q < 4; ++q) {
            float4 v0 = *(const float4*)&OffP[((size_t)q * 4 * 18) * HW + p0 + p4];
            float4 v1 = *(const float4*)&OffP[((size_t)q * 4 * 18) * HW + p1 + p4];
            s0.x += v0.x; s0.y += v0.y; s0.z += v0.z; s0.w += v0.w;
            s1.x += v1.x; s1.y += v1.y; s1.z += v1.z; s1.w += v1.w;
        }
        s0.x += bias0; s0.y += bias0; s0.z += bias0; s0.w += bias0;
        s1.x += bias1; s1.y += bias1; s1.z += bias1; s1.w += bias1;
        float4 o01 = make_float4(s0.x, s1.x, s0.y, s1.y);
        float4 o23 = make_float4(s0.z, s1.z, s0.w, s1.w);
        *(float4*)&outp[p4 * 2]     = o01;
        *(float4*)&outp[p4 * 2 + 4] = o23;
    }
}

// ------------- deformable depthwise 3x3 + BN + SiLU + residual -------------
// XCD-pinned grid (idx%8 = q). 5-row LDS window, stride 68 (conflict-free).
// Paired-corner gathers + interleaved (dy,dx) float2 offset loads.
// |dy|>=1 -> exact global fallback (wave-uniform gate).
__global__ __launch_bounds__(256) void k_deform(
    const float* __restrict__ Hh, const float* __restrict__ Off2,
    const float* __restrict__ Wd, const float* __restrict__ Gb,
    const float* __restrict__ Bb, float* __restrict__ H2)
{
    const int idx = blockIdx.x;
    const int bq  = idx & 31;
    const int y   = idx >> 5;
    const int b   = bq >> 3;
    const int q   = bq & 7;
    const int tid = threadIdx.x;
    const int x = tid & 63;
    const int g = tid >> 6;
    const int pos = y * 64 + x;

    __shared__ __align__(16) float hsw[5][32][68];   // 43.5 KB h window
    __shared__ __align__(16) float wds[9 * 32];      // [k][lc]
    __shared__ float gbs[32], bbs[32];

    for (int i = tid; i < 288; i += 256) {
        int lc = i & 31, k = i >> 5;
        wds[i] = Wd[(q * 32 + lc) * 9 + k];
    }
    if (tid < 32) {
        gbs[tid] = Gb[q * 32 + tid] * BN_RS;
        bbs[tid] = Bb[q * 32 + tid];
    }

    int w0 = y - 2; w0 = w0 < 0 ? 0 : (w0 > 59 ? 59 : w0);
    const float* hq = Hh + ((size_t)(b * 256 + q * 32) << 12);
    #pragma unroll
    for (int it = 0; it < 10; ++it) {
        int i = tid + it * 256;                // 0..2559 float4 units
        int slot = i >> 9, ch = (i >> 4) & 31, x4 = (i & 15) << 2;
        float4 v = *(const float4*)&hq[((size_t)ch << 12) + (w0 + slot) * 64 + x4];
        *(float4*)&hsw[slot][ch][x4] = v;
    }
    __syncthreads();

    float acc[8];
    #pragma unroll
    for (int j = 0; j < 8; ++j) acc[j] = 0.f;

    const float* Ob   = Off2 + ((size_t)b * 9 * HW + pos) * 2;
    const float* hb0  = hq + ((size_t)(g * 8) << 12);
    const float* ldsb = &hsw[0][0][0];

    for (int r = 0; r < 3; ++r) {
        int   rb0[3], rb1[3], lb0[3], lb1[3];
        float wa0[3], wb0[3], wa1[3], wb1[3];
        bool inw = true;
        #pragma unroll
        for (int t = 0; t < 3; ++t) {
            int k = r * 3 + t;
            f32x2a dv = *(const f32x2a*)(Ob + (size_t)k * HW * 2);
            float dy = dv.x, dx = dv.y;
            float py = (float)(y + r - 1) + dy;
            float px = (float)(x + t - 1) + dx;
            float fy0 = floorf(py), fx0 = floorf(px);
            int y0 = (int)fy0, x0 = (int)fx0;
            float fy = py - fy0, fx = px - fx0;
            bool vy0 = ((unsigned)y0 < 64u), vy1 = ((unsigned)(y0 + 1) < 64u);
            bool vx0 = ((unsigned)x0 < 64u), vx1 = ((unsigned)(x0 + 1) < 64u);
            int cy0 = clamp64(y0), cy1 = clamp64(y0 + 1);
            int bx  = x0 < 0 ? 0 : (x0 > 62 ? 62 : x0);
            int d0 = x0 - bx;                  // -1, 0, or 1
            bool o0 = d0 > 0;
            bool o1 = d0 >= 0;
            rb0[t] = cy0 * 64 + bx;
            rb1[t] = cy1 * 64 + bx;
            lb0[t] = (cy0 - w0) * 2176 + bx;   // 2176 = 32*68
            lb1[t] = (cy1 - w0) * 2176 + bx;
            inw = inw && (cy0 >= w0) && (cy1 <= w0 + 4);
            float wy0 = vy0 ? (1.0f - fy) : 0.0f;
            float wy1 = vy1 ? fy : 0.0f;
            float wx0 = vx0 ? (1.0f - fx) : 0.0f;
            float wx1 = vx1 ? fx : 0.0f;
            float wa = (o0 ? 0.0f : wx0) + (o1 ? 0.0f : wx1);
            float wb = (o0 ? wx0 : 0.0f) + (o1 ? wx1 : 0.0f);
            wa0[t] = wa * wy0; wb0[t] = wb * wy0;
            wa1[t] = wa * wy1; wb1[t] = wb * wy1;
        }
        if (__all(inw)) {
            #pragma unroll
            for (int j = 0; j < 8; ++j) {
                const int chb = (g * 8 + j) * 68;
                float a = acc[j];
                #pragma unroll
                for (int t = 0; t < 3; ++t) {
                    f32x2u u0 = *(const f32x2u*)(ldsb + lb0[t] + chb);
                    f32x2u u1 = *(const f32x2u*)(ldsb + lb1[t] + chb);
                    float val = u0.x * wa0[t] + u0.y * wb0[t]
                              + u1.x * wa1[t] + u1.y * wb1[t];
                    a = fmaf(val, wds[(r * 3 + t) * 32 + g * 8 + j], a);
                }
                acc[j] = a;
            }
        } else {
            #pragma unroll
            for (int j = 0; j < 8; ++j) {
                const float* hb = hb0 + ((size_t)j << 12);
                float a = acc[j];
                #pragma unroll
                for (int t = 0; t < 3; ++t) {
                    f32x2u u0 = *(const f32x2u*)(hb + rb0[t]);
                    f32x2u u1 = *(const f32x2u*)(hb + rb1[t]);
                    float val = u0.x * wa0[t] + u0.y * wb0[t]
                              + u1.x * wa1[t] + u1.y * wb1[t];
                    a = fmaf(val, wds[(r * 3 + t) * 32 + g * 8 + j], a);
                }
                acc[j] = a;
            }
        }
    }

    const int ry = (y - w0) * 2176 + x;
    #pragma unroll
    for (int j = 0; j < 8; ++j) {
        int lc = g * 8 + j;
        float t = fmaf(acc[j], gbs[lc], bbs[lc]);
        float res = ldsb[ry + lc * 68];   // row y is always inside the window
        __builtin_nontemporal_store(silu_f(t) + res,
            &H2[((size_t)(b * 256 + q * 32 + lc) << 12) + pos]);
    }
}

// ---------------- SE: global mean over HxW ----------------
__global__ __launch_bounds__(256) void k_se_reduce(
    const float* __restrict__ Y, float* __restrict__ sb)
{
    const int bc = blockIdx.x;
    const float4* p = (const float4*)(Y + (size_t)bc * HW);
    int tid = threadIdx.x;
    float s = 0.f;
    #pragma unroll
    for (int it = 0; it < 4; ++it) {
        float4 v = p[tid + it * 256];
        s += v.x + v.y + v.z + v.w;
    }
    #pragma unroll
    for (int o = 32; o > 0; o >>= 1) s += __shfl_down(s, o);
    __shared__ float red[4];
    if ((tid & 63) == 0) red[tid >> 6] = s;
    __syncthreads();
    if (tid == 0) sb[bc] = (red[0] + red[1] + red[2] + red[3]) * (1.0f / 4096.0f);
}

// ---------------- SE: fc1(silu) + fc2(sigmoid) ----------------
__global__ __launch_bounds__(256) void k_se_fc(
    const float* __restrict__ sb, const float* __restrict__ wf1,
    const float* __restrict__ bf1, const float* __restrict__ wf2,
    const float* __restrict__ bf2, float* __restrict__ s2)
{
    const int b = blockIdx.x;
    const int t = threadIdx.x;
    __shared__ float sv[512];
    __shared__ float s1[32];
    sv[t]       = sb[b * 512 + t];
    sv[t + 256] = sb[b * 512 + t + 256];
    __syncthreads();
    if (t < 32) {
        float a = bf1[t];
        const float* w = wf1 + t * 512;
        for (int i = 0; i < 512; ++i) a = fmaf(w[i], sv[i], a);
        s1[t] = silu_f(a);
    }
    __syncthreads();
    #pragma unroll
    for (int it = 0; it < 2; ++it) {
        int co = t + it * 256;
        float a = bf2[co];
        const float* w = wf2 + co * 32;
        #pragma unroll
        for (int i = 0; i < 32; ++i) a = fmaf(w[i], s1[i], a);
        s2[b * 512 + co] = 1.0f / (1.0f + __expf(-a));
    }
}

// ---------------- final: out *= s ----------------
__global__ __launch_bounds__(256) void k_se_scale(
    float* __restrict__ Y, const float* __restrict__ s2)
{
    size_t i = (size_t)blockIdx.x * 256 + threadIdx.x;
    int bc = (int)(i >> 10);
    float sc = s2[bc];
    float4 v = ((float4*)Y)[i];
    v.x *= sc; v.y *= sc; v.z *= sc; v.w *= sc;
    ((float4*)Y)[i] = v;
}

extern "C" void kernel_launch(void* const* d_in, const int* in_sizes, int n_in,
                              void* d_out, int out_size, void* d_ws, size_t ws_size,
                              hipStream_t stream)
{
    const float* x   = (const float*)d_in[0];
    const float* w1  = (const float*)d_in[1];
    const float* g1  = (const float*)d_in[2];
    const float* b1  = (const float*)d_in[3];
    const float* wof = (const float*)d_in[4];
    const float* bof = (const float*)d_in[5];
    const float* wdw = (const float*)d_in[6];
    const float* gb  = (const float*)d_in[7];
    const float* bbv = (const float*)d_in[8];
    const float* w2  = (const float*)d_in[9];
    const float* g2  = (const float*)d_in[10];
    const float* b2  = (const float*)d_in[11];
    const float* wf1 = (const float*)d_in[12];
    const float* bf1 = (const float*)d_in[13];
    const float* wf2 = (const float*)d_in[14];
    const float* bf2 = (const float*)d_in[15];
    float* out = (float*)d_out;

    const size_t n_h    = 4ull * 256 * HW;        // 4,194,304
    const size_t n_offp = 4ull * 4 * 18 * HW;     // 1,179,648
    const size_t n_off  = 4ull * 18 * HW;         //   294,912 (Off2: 4*9*HW*2, same)
    const size_t n_wt2  = 9 * 32 * 256 / 2;       // bf16 x 73728 as floats
    float* ws = (float*)d_ws;
    float *h, *offp, *offc, *h2, *sb, *s2, *wt2f;
    size_t need = (2 * n_h + n_offp + n_off + 2048 + 2048 + n_wt2 + 1024) * sizeof(float);
    if (ws_size >= need) {
        h = ws; offp = h + n_h; offc = offp + n_offp; h2 = offc + n_off;
        sb = h2 + n_h; s2 = sb + 2048; wt2f = s2 + 2048;
    } else {
        h = out;  // dead before conv2 writes out
        offp = ws; offc = offp + n_offp; h2 = offc + n_off;
        sb = h2 + n_h; s2 = sb + 2048; wt2f = s2 + 2048;
    }
    unsigned short* wt2 = (unsigned short*)wt2f;

    k_conv1x1_mfma<256, 512><<<1024, 256, 0, stream>>>(x, w1, g1, b1, h);
    k_woff_t<<<dim3(9, 32), 256, 0, stream>>>(wof, wt2);
    k_conv_off<<<dim3(64, 4, 4), 256, 0, stream>>>(h, wt2, offp);
    k_off_combine<<<36, 256, 0, stream>>>(offp, bof, offc);
    k_deform<<<2048, 256, 0, stream>>>(h, offc, wdw, gb, bbv, h2);
    k_conv1x1_mfma<512, 256><<<2048, 256, 0, stream>>>(h2, w2, g2, b2, out);
    k_se_reduce<<<2048, 256, 0, stream>>>(out, sb);
    k_se_fc<<<4, 256, 0, stream>>>(sb, wf1, bf1, wf2, bf2, s2);
    k_se_scale<<<8192, 256, 0, stream>>>(out, s2);
}